// Round 4
// baseline (48.134 us; speedup 1.0000x reference)
//
#include <hip/hip_runtime.h>

// loss = (dot(x[0:half], x[half:n]) / rows + 1) / 2, rows = half/1024.
// Row-major => sum_i dot(real_i, fake_i) is a flat dot of the two halves.
//
// Two kernels (R2 lesson: single-dispatch cross-XCD fencing costs ~150us).
// R4 experiment: unroll 4->8 (16 dwordx4 loads in flight/thread) to raise
// memory-level parallelism; theory is the stream is latency-limited, not
// BW-limited (R2 FETCH_SIZE showed half the input is L3-resident).

constexpr int BLOCK = 256;
constexpr int GRID  = 2048;   // 256 CUs x 8 blocks co-resident
constexpr int UNROLL = 8;

__global__ __launch_bounds__(BLOCK) void dot_partial_kernel(
    const float4* __restrict__ a, const float4* __restrict__ b,
    float* __restrict__ partials, long n4)
{
    const long tid    = (long)blockIdx.x * BLOCK + threadIdx.x;
    const long stride = (long)GRID * BLOCK;

    float acc[UNROLL];
    #pragma unroll
    for (int u = 0; u < UNROLL; ++u) acc[u] = 0.f;

    long i = tid;
    for (; i + (UNROLL - 1) * stride < n4; i += UNROLL * stride) {
        float4 xs[UNROLL], ys[UNROLL];
        #pragma unroll
        for (int u = 0; u < UNROLL; ++u) {
            xs[u] = a[i + u * stride];
            ys[u] = b[i + u * stride];
        }
        #pragma unroll
        for (int u = 0; u < UNROLL; ++u)
            acc[u] += xs[u].x * ys[u].x + xs[u].y * ys[u].y +
                      xs[u].z * ys[u].z + xs[u].w * ys[u].w;
    }
    for (; i < n4; i += stride) {   // tail (empty at the bench shape)
        float4 x = a[i]; float4 y = b[i];
        acc[0] += x.x * y.x + x.y * y.y + x.z * y.z + x.w * y.w;
    }

    float r = 0.f;
    #pragma unroll
    for (int u = 0; u < UNROLL; ++u) r += acc[u];

    #pragma unroll
    for (int off = 32; off > 0; off >>= 1)
        r += __shfl_down(r, off, 64);

    __shared__ float s[BLOCK / 64];
    const int lane = threadIdx.x & 63;
    const int wave = threadIdx.x >> 6;
    if (lane == 0) s[wave] = r;
    __syncthreads();
    if (threadIdx.x == 0)
        partials[blockIdx.x] = (s[0] + s[1]) + (s[2] + s[3]);
}

__global__ __launch_bounds__(BLOCK) void finalize_kernel(
    const float4* __restrict__ partials4, float* __restrict__ out,
    float inv_count)
{
    // GRID/4 = 512 float4; 256 threads read 2 each
    float4 p0 = partials4[threadIdx.x];
    float4 p1 = partials4[threadIdx.x + BLOCK];
    float acc = (p0.x + p0.y + p0.z + p0.w) + (p1.x + p1.y + p1.z + p1.w);

    #pragma unroll
    for (int off = 32; off > 0; off >>= 1)
        acc += __shfl_down(acc, off, 64);

    __shared__ float s[BLOCK / 64];
    const int lane = threadIdx.x & 63;
    const int wave = threadIdx.x >> 6;
    if (lane == 0) s[wave] = acc;
    __syncthreads();
    if (threadIdx.x == 0)
        out[0] = (((s[0] + s[1]) + (s[2] + s[3])) * inv_count + 1.0f) * 0.5f;
}

extern "C" void kernel_launch(void* const* d_in, const int* in_sizes, int n_in,
                              void* d_out, int out_size, void* d_ws, size_t ws_size,
                              hipStream_t stream) {
    const float* x = (const float*)d_in[0];
    long n    = (long)in_sizes[0];   // 65536 * 1024
    long half = n / 2;
    long n4   = half / 4;
    long rows = half / 1024;

    const float4* a = (const float4*)x;
    const float4* b = (const float4*)(x + half);
    float* partials = (float*)d_ws;

    dot_partial_kernel<<<GRID, BLOCK, 0, stream>>>(a, b, partials, n4);
    finalize_kernel<<<1, BLOCK, 0, stream>>>((const float4*)partials,
                                             (float*)d_out,
                                             1.0f / (float)rows);
}

// Round 5
// 46.543 us; speedup vs baseline: 1.0342x; 1.0342x over previous
//
#include <hip/hip_runtime.h>

// loss = (dot(x[0:half], x[half:n]) / rows + 1) / 2, rows = half/1024.
// Row-major => sum_i dot(real_i, fake_i) is a flat dot of the two halves.
//
// Two kernels (R2: single-dispatch cross-XCD fencing costs ~150us).
// R5 experiment: block-contiguous chunking (each block streams a contiguous
// 64KB slice of each half) for DRAM row-buffer locality, vs R3's grid-stride
// where every wave jumps 8MB between accesses. Unroll stays 4 (R4: unroll 8
// crossed the 64-VGPR occupancy step and regressed).

constexpr int BLOCK = 256;
constexpr int GRID  = 2048;   // 256 CUs x 8 blocks co-resident

__global__ __launch_bounds__(BLOCK) void dot_partial_kernel(
    const float4* __restrict__ a, const float4* __restrict__ b,
    float* __restrict__ partials, long n4)
{
    const long chunk = n4 / GRID;            // float4 elems per block
    const long base  = (long)blockIdx.x * chunk;
    const float4* __restrict__ A = a + base;
    const float4* __restrict__ B = b + base;

    float acc0 = 0.f, acc1 = 0.f, acc2 = 0.f, acc3 = 0.f;
    long j = threadIdx.x;
    for (; j + 3 * BLOCK < chunk; j += 4 * BLOCK) {
        float4 x0 = A[j];             float4 y0 = B[j];
        float4 x1 = A[j + BLOCK];     float4 y1 = B[j + BLOCK];
        float4 x2 = A[j + 2 * BLOCK]; float4 y2 = B[j + 2 * BLOCK];
        float4 x3 = A[j + 3 * BLOCK]; float4 y3 = B[j + 3 * BLOCK];
        acc0 += x0.x * y0.x + x0.y * y0.y + x0.z * y0.z + x0.w * y0.w;
        acc1 += x1.x * y1.x + x1.y * y1.y + x1.z * y1.z + x1.w * y1.w;
        acc2 += x2.x * y2.x + x2.y * y2.y + x2.z * y2.z + x2.w * y2.w;
        acc3 += x3.x * y3.x + x3.y * y3.y + x3.z * y3.z + x3.w * y3.w;
    }
    for (; j < chunk; j += BLOCK) {          // chunk-size tail
        float4 x = A[j]; float4 y = B[j];
        acc0 += x.x * y.x + x.y * y.y + x.z * y.z + x.w * y.w;
    }
    // global tail if n4 % GRID != 0 (empty at the bench shape)
    const long done = chunk * GRID;
    for (long i = done + (long)blockIdx.x * BLOCK + threadIdx.x; i < n4;
         i += (long)GRID * BLOCK) {
        float4 x = a[i]; float4 y = b[i];
        acc0 += x.x * y.x + x.y * y.y + x.z * y.z + x.w * y.w;
    }
    float acc = (acc0 + acc1) + (acc2 + acc3);

    #pragma unroll
    for (int off = 32; off > 0; off >>= 1)
        acc += __shfl_down(acc, off, 64);

    __shared__ float s[BLOCK / 64];
    const int lane = threadIdx.x & 63;
    const int wave = threadIdx.x >> 6;
    if (lane == 0) s[wave] = acc;
    __syncthreads();
    if (threadIdx.x == 0)
        partials[blockIdx.x] = (s[0] + s[1]) + (s[2] + s[3]);
}

__global__ __launch_bounds__(BLOCK) void finalize_kernel(
    const float4* __restrict__ partials4, float* __restrict__ out,
    float inv_count)
{
    // GRID/4 = 512 float4; 256 threads read 2 each
    float4 p0 = partials4[threadIdx.x];
    float4 p1 = partials4[threadIdx.x + BLOCK];
    float acc = (p0.x + p0.y + p0.z + p0.w) + (p1.x + p1.y + p1.z + p1.w);

    #pragma unroll
    for (int off = 32; off > 0; off >>= 1)
        acc += __shfl_down(acc, off, 64);

    __shared__ float s[BLOCK / 64];
    const int lane = threadIdx.x & 63;
    const int wave = threadIdx.x >> 6;
    if (lane == 0) s[wave] = acc;
    __syncthreads();
    if (threadIdx.x == 0)
        out[0] = (((s[0] + s[1]) + (s[2] + s[3])) * inv_count + 1.0f) * 0.5f;
}

extern "C" void kernel_launch(void* const* d_in, const int* in_sizes, int n_in,
                              void* d_out, int out_size, void* d_ws, size_t ws_size,
                              hipStream_t stream) {
    const float* x = (const float*)d_in[0];
    long n    = (long)in_sizes[0];   // 65536 * 1024
    long half = n / 2;
    long n4   = half / 4;
    long rows = half / 1024;

    const float4* a = (const float4*)x;
    const float4* b = (const float4*)(x + half);
    float* partials = (float*)d_ws;

    dot_partial_kernel<<<GRID, BLOCK, 0, stream>>>(a, b, partials, n4);
    finalize_kernel<<<1, BLOCK, 0, stream>>>((const float4*)partials,
                                             (float*)d_out,
                                             1.0f / (float)rows);
}